// Round 10
// baseline (327.266 us; speedup 1.0000x reference)
//
#include <hip/hip_runtime.h>
#include <stdint.h>

#define S_LEN  4096
#define HID    1024
#define NHEAD  2
#define HDIM   512
#define KS_STRIDE 520   // 512 + 8 pad elems -> bank-floor on QK^T reads
#define LN_EPS 1e-5f
#define PADK   4224     // compacted-key buffer rows (33*128; >= 3*ceil(4096/96)*32 = 4128)
#define CH1    832      // head-1 chunk: 5 splits x 832 covers 4096 (last split 768)

typedef __bf16 bf16x8 __attribute__((ext_vector_type(8)));
typedef float  f32x4  __attribute__((ext_vector_type(4)));

__device__ __forceinline__ float b2f(unsigned short u) {
    return __uint_as_float(((unsigned int)u) << 16);
}
__device__ __forceinline__ unsigned short f2b(float f) {
    unsigned int u = __float_as_uint(f);
    u += 0x7FFFu + ((u >> 16) & 1u);   // round-to-nearest-even
    return (unsigned short)(u >> 16);
}

// async 16B global->LDS (DMA; LDS dest must be wave-uniform base + lane*16;
// the GLOBAL source is per-lane -> index remap through cidx is legal)
__device__ __forceinline__ void async_cp16(const void* g, void* l) {
    __builtin_amdgcn_global_load_lds(
        (const __attribute__((address_space(1))) unsigned int*)g,
        (__attribute__((address_space(3))) unsigned int*)l, 16, 0, 0);
}

// ---- R19 fused front-end, flat 1D grid (4101 blocks):
//   [0,2048)    weights fp32->bf16 (4 matrices)
//   [2048,2052) semb = Ws@sd + bs
//   2052        mask compaction scan -> cidx/nact (tail zero-filled)
//   [2053,4101) Xb = bf16(X)   (kvin is GONE: semb enters K/V as a GEMM bias - R19)
__global__ void k_cvt4s(const float* __restrict__ i0, const float* __restrict__ i1,
                        const float* __restrict__ i2, const float* __restrict__ i3,
                        unsigned short* __restrict__ o0, unsigned short* __restrict__ o1,
                        unsigned short* __restrict__ o2, unsigned short* __restrict__ o3,
                        const float* __restrict__ Ws, const float* __restrict__ sd,
                        const float* __restrict__ bs, float* __restrict__ semb,
                        const int* __restrict__ msk, int* __restrict__ cidx,
                        int* __restrict__ nactp,
                        const float* __restrict__ X, unsigned short* __restrict__ Xb) {
    int b = blockIdx.x, tid = threadIdx.x;
    if (b < 2048) {          // weight conversion
        int w = b >> 9, inner = b & 511;
        const float* in = w == 0 ? i0 : w == 1 ? i1 : w == 2 ? i2 : i3;
        unsigned short* o = w == 0 ? o0 : w == 1 ? o1 : w == 2 ? o2 : o3;
        int i = (inner * 256 + tid) * 8;
        float4 a = *(const float4*)(in + i);
        float4 c = *(const float4*)(in + i + 4);
        unsigned short r[8] = {f2b(a.x), f2b(a.y), f2b(a.z), f2b(a.w),
                               f2b(c.x), f2b(c.y), f2b(c.z), f2b(c.w)};
        *(uint4*)(o + i) = *(const uint4*)r;
        return;
    }
    if (b < 2052) {          // semb
        int j = (b - 2048) * 256 + tid;
        float acc = bs[j];
        const float* row = Ws + j * 64;
        #pragma unroll
        for (int d = 0; d < 64; ++d) acc += row[d] * sd[d];
        semb[j] = acc;
        return;
    }
    if (b == 2052) {         // compaction scan
        __shared__ int cnts[256];
        __shared__ int bases[256];
        __shared__ int nact_s;
        int t = tid;
        int c = 0;
        #pragma unroll
        for (int i = 0; i < 16; ++i) c += (msk[t * 16 + i] != 0);
        cnts[t] = c;
        __syncthreads();
        if (t == 0) {
            int bb = 0;
            for (int k = 0; k < 256; ++k) { bases[k] = bb; bb += cnts[k]; }
            nactp[0] = bb;
            nact_s   = bb;
        }
        __syncthreads();
        int bb = bases[t];
        #pragma unroll
        for (int i = 0; i < 16; ++i)
            if (msk[t * 16 + i] != 0) cidx[bb++] = t * 16 + i;
        for (int j = nact_s + t; j < PADK; j += 256) cidx[j] = 0;  // tail -> key 0 (P-gated)
        return;
    }
    {                        // Xb = bf16(X)
        int idx = ((b - 2053) * 256 + tid) * 8;
        float4 a = *(const float4*)(X + idx);
        float4 c = *(const float4*)(X + idx + 4);
        unsigned short r[8] = {f2b(a.x), f2b(a.y), f2b(a.z), f2b(a.w),
                               f2b(c.x), f2b(c.y), f2b(c.z), f2b(c.w)};
        *(uint4*)(Xb + idx) = *(const uint4*)r;
    }
}

// ---------------- 128x128 GEMM core: C = A @ B^T (+bias), bf16 out ----------------
// R15 dbuf pipeline. ra/rb remap STAGED A/B rows (gathered GEMM). bmode: 0 none,
// 1 col-bias (bias[j] = dot(semb, Brow_j) — K = X@Wk^T + Wk@semb), 2 row-bias
// (bias[i] = dot(semb, Arow_i) — V^T rows). Bias dot runs in the prologue against
// L2-hot weight rows; lands in the fp32 accumulator (tighter than bf16 pre-round).
__device__ __forceinline__
void gemm128(const unsigned short* __restrict__ A,
             const unsigned short* __restrict__ B,
             unsigned short* __restrict__ Cb,
             int bx, int nx, int ldc,
             const int* __restrict__ ra, const int* __restrict__ rb,
             const float* __restrict__ semb, int bmode) {
    __shared__ unsigned short As[2][128 * 32];
    __shared__ unsigned short Bs[2][128 * 32];
    __shared__ float pb[256];
    int tid  = threadIdx.x;
    int wave = tid >> 6, lane = tid & 63;
    int quad = lane >> 4, l16 = lane & 15;
    int wm = wave >> 1, wn = wave & 1;
    int m0 = (bx / nx) * 128, n0 = (bx % nx) * 128;

    // bias partials: thread t = (row t>>1, half t&1); combined at epilogue read
    if (bmode) {
        const unsigned short* wb = (bmode == 1 ? B : A)
            + (size_t)((bmode == 1 ? n0 : m0) + (tid >> 1)) * HID + (tid & 1) * 512;
        const float* se = semb + (tid & 1) * 512;
        float s = 0.f;
        #pragma unroll 8
        for (int d = 0; d < 512; d += 8) {
            bf16x8 w8 = *(const bf16x8*)(wb + d);
            #pragma unroll
            for (int e = 0; e < 8; ++e) s += (float)w8[e] * se[d + e];
        }
        pb[tid] = s;   // visible after the loop's first __syncthreads
    }

    auto stage = [&](int k0, int b) {
        #pragma unroll
        for (int i = 0; i < 2; ++i) {
            int c = tid + i * 256;   // LDS dest c*16B: wave-uniform base + lane*16 -> DMA-legal
            int arow = m0 + (c >> 2);
            if (ra) arow = ra[arow];
            int brow = n0 + (c >> 2);
            if (rb) brow = rb[brow];
            async_cp16(A + (size_t)arow * HID + k0 + (c & 3) * 8, As[b] + c * 8);
            async_cp16(B + (size_t)brow * HID + k0 + (c & 3) * 8, Bs[b] + c * 8);
        }
    };

    f32x4 zero = {0.f, 0.f, 0.f, 0.f};
    f32x4 acc[4][4];
    #pragma unroll
    for (int i = 0; i < 4; ++i)
        #pragma unroll
        for (int j = 0; j < 4; ++j) acc[i][j] = zero;

    stage(0, 0);
    for (int it = 0; it < HID / 32; ++it) {
        int b = it & 1;
        __syncthreads();
        if (it + 1 < HID / 32) stage((it + 1) * 32, b ^ 1);

        bf16x8 af[4], bfr[4];
        #pragma unroll
        for (int i = 0; i < 4; ++i)
            af[i] = *(const bf16x8*)(As[b] + (wm * 64 + i * 16 + l16) * 32 + quad * 8);
        #pragma unroll
        for (int j = 0; j < 4; ++j)
            bfr[j] = *(const bf16x8*)(Bs[b] + (wn * 64 + j * 16 + l16) * 32 + quad * 8);
        #pragma unroll
        for (int i = 0; i < 4; ++i)
            #pragma unroll
            for (int j = 0; j < 4; ++j)
                acc[i][j] = __builtin_amdgcn_mfma_f32_16x16x32_bf16(af[i], bfr[j], acc[i][j], 0, 0, 0);
    }

    #pragma unroll
    for (int i = 0; i < 4; ++i) {
        int rbase = m0 + wm * 64 + i * 16 + quad * 4;
        #pragma unroll
        for (int j = 0; j < 4; ++j) {
            int col = n0 + wn * 64 + j * 16 + l16;
            float bvc = 0.f;
            if (bmode == 1) {
                int cl = wn * 64 + j * 16 + l16;
                bvc = pb[2 * cl] + pb[2 * cl + 1];
            }
            #pragma unroll
            for (int r = 0; r < 4; ++r) {
                float v = acc[i][j][r] + bvc;
                if (bmode == 2) {
                    int rl = wm * 64 + i * 16 + quad * 4 + r;
                    v += pb[2 * rl] + pb[2 * rl + 1];
                }
                Cb[(size_t)(rbase + r) * ldc + col] = f2b(v);
            }
        }
    }
}

// All projections in one flat launch. All A/B streams are Xb or weights (kvin gone).
// R19: Kc/Vtc blocks beyond kcLim = ceil(nact/96)*96 EARLY-EXIT — flash provably never
// reads compacted rows/cols >= kcLim, so the zero-pad tail GEMM work is dead (~16%).
__global__ __launch_bounds__(256)
void k_gemms(const unsigned short* __restrict__ Xb,
             const unsigned short* __restrict__ Wqb,
             const unsigned short* __restrict__ Wkb,
             const unsigned short* __restrict__ Wvb,
             const int* __restrict__ cidx,
             const int* __restrict__ nactp,
             const float* __restrict__ semb,
             unsigned short* __restrict__ Qb,
             unsigned short* __restrict__ Kb1,   // [S_LEN][512]  head-1 K
             unsigned short* __restrict__ Vt1,   // [512][S_LEN]  head-1 V^T
             unsigned short* __restrict__ Kc,    // [PADK][512]   compacted head-0 K
             unsigned short* __restrict__ Vtc) { // [512][PADK]   compacted head-0 V^T
    int g = blockIdx.x;
    int b = (g & 7) * 97 + (g >> 3);   // bijective XCD swizzle (776 % 8 == 0)
    if (b < 256) {
        gemm128(Xb, Wqb, Qb, b, 8, HID, nullptr, nullptr, semb, 0);
    } else if (b < 384) {
        gemm128(Xb, Wkb + 512 * HID, Kb1, b - 256, 4, 512, nullptr, nullptr, semb, 1);
    } else if (b < 512) {
        gemm128(Wvb + 512 * HID, Xb, Vt1, b - 384, 32, S_LEN, nullptr, nullptr, semb, 2);
    } else if (b < 644) {
        int bb = b - 512;
        int kcLim = ((nactp[0] + 95) / 96) * 96;
        if ((bb >> 2) * 128 >= kcLim) return;          // row-panel never read by flash
        gemm128(Xb, Wkb, Kc, bb, 4, 512, cidx, nullptr, semb, 1);
    } else {
        int bb = b - 644;
        int kcLim = ((nactp[0] + 95) / 96) * 96;
        if ((bb % 33) * 128 >= kcLim) return;          // col-panel never read by flash
        gemm128(Wvb, Xb, Vtc, bb, 33, PADK, nullptr, cidx, semb, 2);
    }
}

// ------- out-projection 64x128 tile, fused split-combine + normalize + residual -------
// Opart layout: head0 slots 0..2, head1 slots 3..7, each [S][512] (per-head local cols).
__global__ __launch_bounds__(256)
void k_gemm_o(const unsigned short* __restrict__ Opart,
              const float* __restrict__ Lbuf,    // [8][S]
              const unsigned short* __restrict__ B,
              float* __restrict__ Cf,
              const float* __restrict__ Xres) {
    __shared__ unsigned short As[2][64 * 32];
    __shared__ unsigned short Bs[2][128 * 32];
    const size_t SH2 = (size_t)S_LEN * 512;
    int tid  = threadIdx.x;
    int wave = tid >> 6, lane = tid & 63;
    int quad = lane >> 4, l16 = lane & 15;
    int bx = (blockIdx.x & 7) * 64 + (blockIdx.x >> 3);
    int m0 = (bx >> 3) * 64, n0 = (bx & 7) * 128;

    int arow  = m0 + (tid >> 2);
    int acol8 = (tid & 3) * 8;
    float rinv[NHEAD];
    {
        float l0 = Lbuf[arow] + Lbuf[S_LEN + arow] + Lbuf[2 * S_LEN + arow];
        float l1 = 0.f;
        #pragma unroll
        for (int z = 3; z < 8; ++z) l1 += Lbuf[z * S_LEN + arow];
        rinv[0] = 1.f / l0;
        rinv[1] = 1.f / l1;
    }

    auto stageB = [&](int k0, int b) {
        #pragma unroll
        for (int i = 0; i < 2; ++i) {
            int c = tid + i * 256;
            async_cp16(B + (n0 + (c >> 2)) * HID + k0 + (c & 3) * 8, Bs[b] + c * 8);
        }
    };
    auto stageA = [&](int k0, int b) {
        int h = k0 >> 9;
        float rv = rinv[h];
        int lk = (k0 & 511) + acol8;
        const unsigned short* ap = Opart + (h ? 3 * SH2 : 0) + (size_t)arow * 512 + lk;
        float s[8] = {0.f, 0.f, 0.f, 0.f, 0.f, 0.f, 0.f, 0.f};
        int nz = h ? 5 : 3;
        for (int z = 0; z < nz; ++z) {
            uint4 v = *(const uint4*)(ap + (size_t)z * SH2);
            unsigned short us[8];
            *(uint4*)us = v;
            #pragma unroll
            for (int e = 0; e < 8; ++e) s[e] += b2f(us[e]);
        }
        unsigned short o8[8];
        #pragma unroll
        for (int e = 0; e < 8; ++e) o8[e] = f2b(s[e] * rv);
        *(uint4*)(As[b] + tid * 8) = *(const uint4*)o8;
    };

    f32x4 zero = {0.f, 0.f, 0.f, 0.f};
    f32x4 acc[4][2];
    #pragma unroll
    for (int i = 0; i < 4; ++i)
        #pragma unroll
        for (int j = 0; j < 2; ++j) acc[i][j] = zero;

    stageB(0, 0);
    stageA(0, 0);
    for (int it = 0; it < HID / 32; ++it) {
        int b = it & 1;
        __syncthreads();
        if (it + 1 < HID / 32) {
            stageB((it + 1) * 32, b ^ 1);
            stageA((it + 1) * 32, b ^ 1);
        }
        bf16x8 af[4], bfr[2];
        #pragma unroll
        for (int i = 0; i < 4; ++i)
            af[i] = *(const bf16x8*)(As[b] + (i * 16 + l16) * 32 + quad * 8);
        #pragma unroll
        for (int j = 0; j < 2; ++j)
            bfr[j] = *(const bf16x8*)(Bs[b] + (wave * 32 + j * 16 + l16) * 32 + quad * 8);
        #pragma unroll
        for (int i = 0; i < 4; ++i)
            #pragma unroll
            for (int j = 0; j < 2; ++j)
                acc[i][j] = __builtin_amdgcn_mfma_f32_16x16x32_bf16(af[i], bfr[j], acc[i][j], 0, 0, 0);
    }

    #pragma unroll
    for (int i = 0; i < 4; ++i) {
        int rbase = m0 + i * 16 + quad * 4;
        #pragma unroll
        for (int j = 0; j < 2; ++j) {
            int col = n0 + wave * 32 + j * 16 + l16;
            #pragma unroll
            for (int r = 0; r < 4; ++r) {
                size_t o = (size_t)(rbase + r) * HID + col;
                Cf[o] = acc[i][j][r] + Xres[o];
            }
        }
    }
}

// ---------------- flash attention: 128 queries x one (head, key-split) ----------------
// R8 inner loop EXACTLY (proven 85us). head-0: Kc/Vtc compacted (3 splits); head-1:
// Kb1/Vt1 (5 splits, CH1=832). Validity = (key < nact); tails P-gated to 0.
__global__ __launch_bounds__(512, 2)
void k_flash(const unsigned short* __restrict__ Q,
             const unsigned short* __restrict__ Kb1,
             const unsigned short* __restrict__ Vt1,
             const unsigned short* __restrict__ Kc,
             const unsigned short* __restrict__ Vtc,
             const int* __restrict__ nactp,
             unsigned short* __restrict__ Opart,       // [8][S][512] per-head local cols
             float* __restrict__ Lbuf) {               // [8][S]
    __shared__ unsigned short Ks[2][32 * KS_STRIDE];
    __shared__ __bf16 Ps[2][128][40];
    int tid  = threadIdx.x;
    int wave = tid >> 6, lane = tid & 63;
    int quad = lane >> 4, l16 = lane & 15;
    int x = blockIdx.x, qtile = blockIdx.y;
    int head  = (x >= 3) ? 1 : 0;
    int split = head ? x - 3 : x;
    int nact  = nactp[0];

    int nit, base, vrs;
    const unsigned short *Ksrc, *Vsrc;
    if (head == 0) {
        nit  = (nact + 95) / 96;          // ceil(nact / (3 splits * 32))
        base = split * nit * 32;
        Ksrc = Kc;  Vsrc = Vtc; vrs = PADK;
    } else {
        base = split * CH1;
        nit  = min(CH1 >> 5, (S_LEN - base) >> 5);
        Ksrc = Kb1; Vsrc = Vt1; vrs = S_LEN;
    }

    // Q fragments (A-operand: A[m=lane&15][k=quad*8+j]), pinned in registers
    int qrow = qtile * 128 + wave * 16 + l16;
    const unsigned short* qp = Q + qrow * HID + head * HDIM;
    bf16x8 qf[16];
    #pragma unroll
    for (int t = 0; t < 16; ++t) qf[t] = *(const bf16x8*)(qp + t * 32 + quad * 8);

    float lsum[4];
    #pragma unroll
    for (int r = 0; r < 4; ++r) lsum[r] = 0.f;
    f32x4 zero = {0.f, 0.f, 0.f, 0.f};
    f32x4 oacc[8][4];
    #pragma unroll
    for (int mt = 0; mt < 8; ++mt)
        #pragma unroll
        for (int nt = 0; nt < 4; ++nt) oacc[mt][nt] = zero;

    const float scale = 0.044194173824159216f; // 1/sqrt(512)
    const unsigned short* vptr = Vsrc + (size_t)(wave * 64 + l16) * vrs + base + quad * 8;

    auto stageK = [&](int kt, int buf) {
        int kb = base + kt * 32;
        #pragma unroll
        for (int i = 0; i < 4; ++i) {
            int c = tid + i * 512;
            int row = c >> 6, col = (c & 63) * 8;   // per-wave: row uniform, col = lane*16B
            async_cp16(Ksrc + (size_t)(kb + row) * 512 + col, &Ks[buf][row * KS_STRIDE + col]);
        }
    };

    if (nit > 0) stageK(0, 0);

    bf16x8 vf[4];
    for (int it = 0; it < nit; ++it) {
        int cur = it & 1;
        __syncthreads();   // Ks[cur] DMA drained; Ps[cur] free; Ps[cur^1] written

        if (it + 1 < nit) stageK(it + 1, cur ^ 1);

        __builtin_amdgcn_s_setprio(1);
        if (it > 0) {
            #pragma unroll
            for (int mt = 0; mt < 8; ++mt) {
                bf16x8 pf = *(const bf16x8*)&Ps[cur ^ 1][mt * 16 + l16][quad * 8];
                #pragma unroll
                for (int nt = 0; nt < 4; ++nt)
                    oacc[mt][nt] = __builtin_amdgcn_mfma_f32_16x16x32_bf16(pf, vf[nt], oacc[mt][nt], 0, 0, 0);
            }
        }

        // V prefetch for THIS tile (16 VGPR carry, proven budget)
        #pragma unroll
        for (int nt = 0; nt < 4; ++nt)
            vf[nt] = *(const bf16x8*)(vptr + (size_t)nt * 16 * vrs + it * 32);

        // S = Q K^T
        f32x4 sacc[2];
        sacc[0] = zero; sacc[1] = zero;
        #pragma unroll
        for (int nt = 0; nt < 2; ++nt)
            #pragma unroll
            for (int t = 0; t < 16; ++t) {
                bf16x8 kf = *(const bf16x8*)&Ks[cur][(nt * 16 + l16) * KS_STRIDE + t * 32 + quad * 8];
                sacc[nt] = __builtin_amdgcn_mfma_f32_16x16x32_bf16(qf[t], kf, sacc[nt], 0, 0, 0);
            }
        __builtin_amdgcn_s_setprio(0);

        // validity: compacted head-0 keys need only the nact bound; head-1 all valid
        bool keep0 = true, keep1 = true;
        if (head == 0) {
            int kb = base + it * 32;
            keep0 = kb + l16 < nact;
            keep1 = kb + 16 + l16 < nact;
        }
        #pragma unroll
        for (int r = 0; r < 4; ++r) {
            float p0 = keep0 ? __expf(fminf(sacc[0][r] * scale, 30.f)) : 0.f;
            float p1 = keep1 ? __expf(fminf(sacc[1][r] * scale, 30.f)) : 0.f;
            lsum[r] += p0 + p1;
            Ps[cur][wave * 16 + quad * 4 + r][l16]      = (__bf16)p0;
            Ps[cur][wave * 16 + quad * 4 + r][16 + l16] = (__bf16)p1;
        }
    }

    // epilogue PV for the last tile
    if (nit > 0) {
        int lastb = (nit - 1) & 1;
        __syncthreads();
        #pragma unroll
        for (int mt = 0; mt < 8; ++mt) {
            bf16x8 pf = *(const bf16x8*)&Ps[lastb][mt * 16 + l16][quad * 8];
            #pragma unroll
            for (int nt = 0; nt < 4; ++nt)
                oacc[mt][nt] = __builtin_amdgcn_mfma_f32_16x16x32_bf16(pf, vf[nt], oacc[mt][nt], 0, 0, 0);
        }
    }

    // l-reduction across the 16 lanes of this quad
    #pragma unroll
    for (int r = 0; r < 4; ++r) {
        float s = lsum[r];
        #pragma unroll
        for (int off = 1; off < 16; off <<= 1)
            s += __shfl_xor(s, off, 64);
        lsum[r] = s;
    }
    int slot = head ? 3 + split : split;
    int lrow = qtile * 128 + wave * 16 + quad * 4;
    if (l16 == 0) {
        #pragma unroll
        for (int r = 0; r < 4; ++r)
            Lbuf[slot * S_LEN + lrow + r] = lsum[r];
    }
    // O epilogue: per-head local cols (512-wide)
    unsigned short* op = Opart + (size_t)slot * S_LEN * 512;
    #pragma unroll
    for (int mt = 0; mt < 8; ++mt)
        #pragma unroll
        for (int nt = 0; nt < 4; ++nt)
            #pragma unroll
            for (int r = 0; r < 4; ++r)
                op[(qtile * 128 + mt * 16 + quad * 4 + r) * 512 +
                   wave * 64 + nt * 16 + l16] = f2b(oacc[mt][nt][r]);
}

// ---------------- per-row LayerNorm over H=1024 (fp32 in, fp32 out) ----------------
__global__ __launch_bounds__(256)
void k_ln(const float* __restrict__ res,
          const float* __restrict__ w,
          const float* __restrict__ b,
          float* __restrict__ out) {
    __shared__ float red[8];
    int s = blockIdx.x, tid = threadIdx.x;
    const float* row = res + s * HID;
    float x[4], s1 = 0.f, s2 = 0.f;
    #pragma unroll
    for (int i = 0; i < 4; ++i) {
        x[i] = row[tid + i * 256];
        s1 += x[i]; s2 += x[i] * x[i];
    }
    #pragma unroll
    for (int off = 1; off < 64; off <<= 1) {
        s1 += __shfl_xor(s1, off, 64);
        s2 += __shfl_xor(s2, off, 64);
    }
    int wave = tid >> 6;
    if ((tid & 63) == 0) { red[wave] = s1; red[4 + wave] = s2; }
    __syncthreads();
    s1 = red[0] + red[1] + red[2] + red[3];
    s2 = red[4] + red[5] + red[6] + red[7];
    float mu   = s1 * (1.f / HID);
    float var  = s2 * (1.f / HID) - mu * mu;
    float rstd = rsqrtf(var + LN_EPS);
    #pragma unroll
    for (int i = 0; i < 4; ++i) {
        int col = tid + i * 256;
        out[s * HID + col] = (x[i] - mu) * rstd * w[col] + b[col];
    }
}

extern "C" void kernel_launch(void* const* d_in, const int* in_sizes, int n_in,
                              void* d_out, int out_size, void* d_ws, size_t ws_size,
                              hipStream_t stream) {
    const float* X   = (const float*)d_in[0];
    const float* sd  = (const float*)d_in[1];
    const int*   msk = (const int*)d_in[2];
    const float* Wq  = (const float*)d_in[3];
    const float* Wk  = (const float*)d_in[4];
    const float* Wv  = (const float*)d_in[5];
    const float* Wo  = (const float*)d_in[6];
    const float* Wsp = (const float*)d_in[7];
    const float* bsp = (const float*)d_in[8];
    const float* lw  = (const float*)d_in[9];
    const float* lb  = (const float*)d_in[10];
    float* out = (float*)d_out;

    // Workspace map — 89MB proven envelope (R7 lesson). kvin region now unused.
    char* ws = (char*)d_ws;
    const size_t MB = 1ull << 20;
    float*          semb  = (float*)(ws);                     // 4 KB @0
    int*            cidx  = (int*)(ws + (16 << 10));          // 16.9 KB @16K (PADK ints)
    int*            nactp = (int*)(ws + (48 << 10));          // 4 B @48K
    float*          Lbuf  = (float*)(ws + (1ull << 16));      // 128 KB @64K (8 slots x S)
    unsigned short* Xb    = (unsigned short*)(ws + 1 * MB);   // 8 MB
    unsigned short* Qb    = (unsigned short*)(ws + 17 * MB);  // 8 MB
    unsigned short* Kb1   = (unsigned short*)(ws + 25 * MB);  // 4 MB [S][512]
    unsigned short* Vt1   = (unsigned short*)(ws + 29 * MB);  // 4 MB [512][S]
    unsigned short* Kc    = (unsigned short*)(ws + 33 * MB);  // 4.125 MB [PADK][512]
    unsigned short* Vtc   = (unsigned short*)(ws + 37 * MB + (256 << 10)); // 4.125 MB
    unsigned short* Wqb   = (unsigned short*)(ws + 49 * MB);  // 2 MB
    unsigned short* Wkb   = (unsigned short*)(ws + 51 * MB);  // 2 MB
    unsigned short* Wvb   = (unsigned short*)(ws + 53 * MB);  // 2 MB
    unsigned short* Wob   = (unsigned short*)(ws + 55 * MB);  // 2 MB
    float*          resf  = (float*)(ws + 17 * MB);           // 16 MB over dead Qb/Kb1/Vt1
    unsigned short* Opart = (unsigned short*)(ws + 57 * MB);  // 32 MB [8][S][512] -> 89 MB

    // fused front-end: weights cvt + semb + scan + Xb cvt (4101 flat blocks)
    k_cvt4s<<<dim3(4101), dim3(256), 0, stream>>>(
        Wq, Wk, Wv, Wo, Wqb, Wkb, Wvb, Wob, Wsp, sd, bsp, semb, msk, cidx, nactp, X, Xb);

    // all projections (Q, K/V head-1, compacted K/V head-0 with bias + early-exit)
    k_gemms<<<dim3(776), dim3(256), 0, stream>>>(
        Xb, Wqb, Wkb, Wvb, cidx, nactp, semb, Qb, Kb1, Vt1, Kc, Vtc);

    // asymmetric splits: x 0..2 = head0 (compacted), x 3..7 = head1; y = qtile (32)
    k_flash<<<dim3(8, S_LEN / 128), dim3(512), 0, stream>>>(
        Qb, Kb1, Vt1, Kc, Vtc, nactp, Opart, Lbuf);

    // out-projection with fused split-combine + normalize + residual
    k_gemm_o<<<dim3(512), dim3(256), 0, stream>>>(Opart, Lbuf, Wob, resf, X);
    k_ln<<<dim3(S_LEN), dim3(256), 0, stream>>>(resf, lw, lb, out);
}

// Round 11
// 311.706 us; speedup vs baseline: 1.0499x; 1.0499x over previous
//
#include <hip/hip_runtime.h>
#include <stdint.h>

#define S_LEN  4096
#define HID    1024
#define NHEAD  2
#define HDIM   512
#define KS_STRIDE 520   // 512 + 8 pad elems -> bank-floor on QK^T reads
#define LN_EPS 1e-5f
#define PADK   4224     // compacted-key buffer rows (33*128; >= 3*ceil(4096/96)*32 = 4128)
#define CH1    832      // head-1 chunk: 5 splits x 832 covers 4096 (last split 768)

typedef __bf16 bf16x8 __attribute__((ext_vector_type(8)));
typedef float  f32x4  __attribute__((ext_vector_type(4)));

__device__ __forceinline__ float b2f(unsigned short u) {
    return __uint_as_float(((unsigned int)u) << 16);
}
__device__ __forceinline__ unsigned short f2b(float f) {
    unsigned int u = __float_as_uint(f);
    u += 0x7FFFu + ((u >> 16) & 1u);   // round-to-nearest-even
    return (unsigned short)(u >> 16);
}

// async 16B global->LDS (DMA; LDS dest must be wave-uniform base + lane*16;
// the GLOBAL source is per-lane -> index remap through cidx is legal)
__device__ __forceinline__ void async_cp16(const void* g, void* l) {
    __builtin_amdgcn_global_load_lds(
        (const __attribute__((address_space(1))) unsigned int*)g,
        (__attribute__((address_space(3))) unsigned int*)l, 16, 0, 0);
}

// ---- R20 fused front-end, flat 1D grid (4109 blocks):
//   [0,2048)    weights fp32->bf16 (4 matrices)
//   [2048,2052) semb = Ws@sd + bs
//   2052        mask compaction scan -> cidx/nact (tail zero-filled)
//   [2053,4101) Xb = bf16(X)
//   [4101,4109) kbias/vbias: bias_j = dot(W_row_j, semb), semb REBUILT locally in LDS
//               (no intra-kernel range dependency). R10's per-block bias prologue in
//               k_gemms (serial 1024-FMA chain + 256KB weight re-read per block) was the
//               115us regression — bias is now computed ONCE here (2M MACs, 8 blocks).
__global__ void k_cvt4s(const float* __restrict__ i0, const float* __restrict__ i1,
                        const float* __restrict__ i2, const float* __restrict__ i3,
                        unsigned short* __restrict__ o0, unsigned short* __restrict__ o1,
                        unsigned short* __restrict__ o2, unsigned short* __restrict__ o3,
                        const float* __restrict__ Ws, const float* __restrict__ sd,
                        const float* __restrict__ bs, float* __restrict__ semb,
                        const int* __restrict__ msk, int* __restrict__ cidx,
                        int* __restrict__ nactp,
                        const float* __restrict__ X, unsigned short* __restrict__ Xb,
                        const float* __restrict__ Wkf, const float* __restrict__ Wvf,
                        float* __restrict__ kbias, float* __restrict__ vbias) {
    int b = blockIdx.x, tid = threadIdx.x;
    if (b < 2048) {          // weight conversion
        int w = b >> 9, inner = b & 511;
        const float* in = w == 0 ? i0 : w == 1 ? i1 : w == 2 ? i2 : i3;
        unsigned short* o = w == 0 ? o0 : w == 1 ? o1 : w == 2 ? o2 : o3;
        int i = (inner * 256 + tid) * 8;
        float4 a = *(const float4*)(in + i);
        float4 c = *(const float4*)(in + i + 4);
        unsigned short r[8] = {f2b(a.x), f2b(a.y), f2b(a.z), f2b(a.w),
                               f2b(c.x), f2b(c.y), f2b(c.z), f2b(c.w)};
        *(uint4*)(o + i) = *(const uint4*)r;
        return;
    }
    if (b < 2052) {          // semb (global copy, kept for potential reuse)
        int j = (b - 2048) * 256 + tid;
        float acc = bs[j];
        const float* row = Ws + j * 64;
        #pragma unroll
        for (int d = 0; d < 64; ++d) acc += row[d] * sd[d];
        semb[j] = acc;
        return;
    }
    if (b == 2052) {         // compaction scan
        __shared__ int cnts[256];
        __shared__ int bases[256];
        __shared__ int nact_s;
        int t = tid;
        int c = 0;
        #pragma unroll
        for (int i = 0; i < 16; ++i) c += (msk[t * 16 + i] != 0);
        cnts[t] = c;
        __syncthreads();
        if (t == 0) {
            int bb = 0;
            for (int k = 0; k < 256; ++k) { bases[k] = bb; bb += cnts[k]; }
            nactp[0] = bb;
            nact_s   = bb;
        }
        __syncthreads();
        int bb = bases[t];
        #pragma unroll
        for (int i = 0; i < 16; ++i)
            if (msk[t * 16 + i] != 0) cidx[bb++] = t * 16 + i;
        for (int j = nact_s + t; j < PADK; j += 256) cidx[j] = 0;  // tail -> key 0 (P-gated)
        return;
    }
    if (b < 4101) {          // Xb = bf16(X)
        int idx = ((b - 2053) * 256 + tid) * 8;
        float4 a = *(const float4*)(X + idx);
        float4 c = *(const float4*)(X + idx + 4);
        unsigned short r[8] = {f2b(a.x), f2b(a.y), f2b(a.z), f2b(a.w),
                               f2b(c.x), f2b(c.y), f2b(c.z), f2b(c.w)};
        *(uint4*)(Xb + idx) = *(const uint4*)r;
        return;
    }
    {                        // kbias (b 4101..4104) / vbias (b 4105..4108), fp32 weights
        __shared__ float se[HID];
        #pragma unroll
        for (int i = 0; i < 4; ++i) {
            int j = tid * 4 + i;
            float acc = bs[j];
            const float* row = Ws + j * 64;
            #pragma unroll
            for (int d = 0; d < 64; ++d) acc += row[d] * sd[d];
            se[j] = acc;
        }
        __syncthreads();
        int r = b - 4101;
        bool isV = r >= 4;
        int j = (r & 3) * 256 + tid;         // output feature 0..1023
        const float* wrow = (isV ? Wvf : Wkf) + (size_t)j * HID;
        float s = 0.f;
        for (int d = 0; d < HID; d += 4) {
            float4 w4 = *(const float4*)(wrow + d);
            s += w4.x * se[d] + w4.y * se[d + 1] + w4.z * se[d + 2] + w4.w * se[d + 3];
        }
        (isV ? vbias : kbias)[j] = s;
    }
}

// ---------------- 128x128 GEMM core: C = A @ B^T (+bias), bf16 out ----------------
// R15 dbuf pipeline. ra/rb remap STAGED A/B rows (gathered GEMM). bmode: 0 none,
// 1 col-bias (bias[col], K-type), 2 row-bias (bias[row], V^T-type). Bias is a
// PRECOMPUTED table (L2-hot, few KB) read at the epilogue — 4-16 scalar loads,
// zero prologue (R10 lesson: per-block bias dots serialized the whole kernel).
__device__ __forceinline__
void gemm128(const unsigned short* __restrict__ A,
             const unsigned short* __restrict__ B,
             unsigned short* __restrict__ Cb,
             int bx, int nx, int ldc,
             const int* __restrict__ ra, const int* __restrict__ rb,
             const float* __restrict__ bias, int bmode) {
    __shared__ unsigned short As[2][128 * 32];
    __shared__ unsigned short Bs[2][128 * 32];
    int tid  = threadIdx.x;
    int wave = tid >> 6, lane = tid & 63;
    int quad = lane >> 4, l16 = lane & 15;
    int wm = wave >> 1, wn = wave & 1;
    int m0 = (bx / nx) * 128, n0 = (bx % nx) * 128;

    auto stage = [&](int k0, int b) {
        #pragma unroll
        for (int i = 0; i < 2; ++i) {
            int c = tid + i * 256;   // LDS dest c*16B: wave-uniform base + lane*16 -> DMA-legal
            int arow = m0 + (c >> 2);
            if (ra) arow = ra[arow];
            int brow = n0 + (c >> 2);
            if (rb) brow = rb[brow];
            async_cp16(A + (size_t)arow * HID + k0 + (c & 3) * 8, As[b] + c * 8);
            async_cp16(B + (size_t)brow * HID + k0 + (c & 3) * 8, Bs[b] + c * 8);
        }
    };

    f32x4 zero = {0.f, 0.f, 0.f, 0.f};
    f32x4 acc[4][4];
    #pragma unroll
    for (int i = 0; i < 4; ++i)
        #pragma unroll
        for (int j = 0; j < 4; ++j) acc[i][j] = zero;

    stage(0, 0);
    for (int it = 0; it < HID / 32; ++it) {
        int b = it & 1;
        __syncthreads();
        if (it + 1 < HID / 32) stage((it + 1) * 32, b ^ 1);

        bf16x8 af[4], bfr[4];
        #pragma unroll
        for (int i = 0; i < 4; ++i)
            af[i] = *(const bf16x8*)(As[b] + (wm * 64 + i * 16 + l16) * 32 + quad * 8);
        #pragma unroll
        for (int j = 0; j < 4; ++j)
            bfr[j] = *(const bf16x8*)(Bs[b] + (wn * 64 + j * 16 + l16) * 32 + quad * 8);
        #pragma unroll
        for (int i = 0; i < 4; ++i)
            #pragma unroll
            for (int j = 0; j < 4; ++j)
                acc[i][j] = __builtin_amdgcn_mfma_f32_16x16x32_bf16(af[i], bfr[j], acc[i][j], 0, 0, 0);
    }

    #pragma unroll
    for (int i = 0; i < 4; ++i) {
        int rbase = m0 + wm * 64 + i * 16 + quad * 4;
        float brow[4];
        if (bmode == 2) {
            #pragma unroll
            for (int r = 0; r < 4; ++r) brow[r] = bias[rbase + r];
        }
        #pragma unroll
        for (int j = 0; j < 4; ++j) {
            int col = n0 + wn * 64 + j * 16 + l16;
            float bvc = (bmode == 1) ? bias[col] : 0.f;
            #pragma unroll
            for (int r = 0; r < 4; ++r) {
                float v = acc[i][j][r] + bvc;
                if (bmode == 2) v += brow[r];
                Cb[(size_t)(rbase + r) * ldc + col] = f2b(v);
            }
        }
    }
}

// All projections in one flat launch. K/V take Xb directly; semb enters as the
// precomputed kbias/vbias tables. Kc/Vtc tail blocks beyond kcLim EARLY-EXIT.
__global__ __launch_bounds__(256)
void k_gemms(const unsigned short* __restrict__ Xb,
             const unsigned short* __restrict__ Wqb,
             const unsigned short* __restrict__ Wkb,
             const unsigned short* __restrict__ Wvb,
             const int* __restrict__ cidx,
             const int* __restrict__ nactp,
             const float* __restrict__ kb,
             const float* __restrict__ vb,
             unsigned short* __restrict__ Qb,
             unsigned short* __restrict__ Kb1,   // [S_LEN][512]  head-1 K
             unsigned short* __restrict__ Vt1,   // [512][S_LEN]  head-1 V^T
             unsigned short* __restrict__ Kc,    // [PADK][512]   compacted head-0 K
             unsigned short* __restrict__ Vtc) { // [512][PADK]   compacted head-0 V^T
    int g = blockIdx.x;
    int b = (g & 7) * 97 + (g >> 3);   // bijective XCD swizzle (776 % 8 == 0)
    if (b < 256) {
        gemm128(Xb, Wqb, Qb, b, 8, HID, nullptr, nullptr, nullptr, 0);
    } else if (b < 384) {
        gemm128(Xb, Wkb + 512 * HID, Kb1, b - 256, 4, 512, nullptr, nullptr, kb + 512, 1);
    } else if (b < 512) {
        gemm128(Wvb + 512 * HID, Xb, Vt1, b - 384, 32, S_LEN, nullptr, nullptr, vb + 512, 2);
    } else if (b < 644) {
        int bb = b - 512;
        int kcLim = ((nactp[0] + 95) / 96) * 96;
        if ((bb >> 2) * 128 >= kcLim) return;          // row-panel never read by flash
        gemm128(Xb, Wkb, Kc, bb, 4, 512, cidx, nullptr, kb, 1);
    } else {
        int bb = b - 644;
        int kcLim = ((nactp[0] + 95) / 96) * 96;
        if ((bb % 33) * 128 >= kcLim) return;          // col-panel never read by flash
        gemm128(Wvb, Xb, Vtc, bb, 33, PADK, nullptr, cidx, vb, 2);
    }
}

// ------- out-projection 64x128 tile, fused split-combine + normalize + residual -------
// Opart layout: head0 slots 0..2, head1 slots 3..7, each [S][512] (per-head local cols).
__global__ __launch_bounds__(256)
void k_gemm_o(const unsigned short* __restrict__ Opart,
              const float* __restrict__ Lbuf,    // [8][S]
              const unsigned short* __restrict__ B,
              float* __restrict__ Cf,
              const float* __restrict__ Xres) {
    __shared__ unsigned short As[2][64 * 32];
    __shared__ unsigned short Bs[2][128 * 32];
    const size_t SH2 = (size_t)S_LEN * 512;
    int tid  = threadIdx.x;
    int wave = tid >> 6, lane = tid & 63;
    int quad = lane >> 4, l16 = lane & 15;
    int bx = (blockIdx.x & 7) * 64 + (blockIdx.x >> 3);
    int m0 = (bx >> 3) * 64, n0 = (bx & 7) * 128;

    int arow  = m0 + (tid >> 2);
    int acol8 = (tid & 3) * 8;
    float rinv[NHEAD];
    {
        float l0 = Lbuf[arow] + Lbuf[S_LEN + arow] + Lbuf[2 * S_LEN + arow];
        float l1 = 0.f;
        #pragma unroll
        for (int z = 3; z < 8; ++z) l1 += Lbuf[z * S_LEN + arow];
        rinv[0] = 1.f / l0;
        rinv[1] = 1.f / l1;
    }

    auto stageB = [&](int k0, int b) {
        #pragma unroll
        for (int i = 0; i < 2; ++i) {
            int c = tid + i * 256;
            async_cp16(B + (n0 + (c >> 2)) * HID + k0 + (c & 3) * 8, Bs[b] + c * 8);
        }
    };
    auto stageA = [&](int k0, int b) {
        int h = k0 >> 9;
        float rv = rinv[h];
        int lk = (k0 & 511) + acol8;
        const unsigned short* ap = Opart + (h ? 3 * SH2 : 0) + (size_t)arow * 512 + lk;
        float s[8] = {0.f, 0.f, 0.f, 0.f, 0.f, 0.f, 0.f, 0.f};
        int nz = h ? 5 : 3;
        for (int z = 0; z < nz; ++z) {
            uint4 v = *(const uint4*)(ap + (size_t)z * SH2);
            unsigned short us[8];
            *(uint4*)us = v;
            #pragma unroll
            for (int e = 0; e < 8; ++e) s[e] += b2f(us[e]);
        }
        unsigned short o8[8];
        #pragma unroll
        for (int e = 0; e < 8; ++e) o8[e] = f2b(s[e] * rv);
        *(uint4*)(As[b] + tid * 8) = *(const uint4*)o8;
    };

    f32x4 zero = {0.f, 0.f, 0.f, 0.f};
    f32x4 acc[4][2];
    #pragma unroll
    for (int i = 0; i < 4; ++i)
        #pragma unroll
        for (int j = 0; j < 2; ++j) acc[i][j] = zero;

    stageB(0, 0);
    stageA(0, 0);
    for (int it = 0; it < HID / 32; ++it) {
        int b = it & 1;
        __syncthreads();
        if (it + 1 < HID / 32) {
            stageB((it + 1) * 32, b ^ 1);
            stageA((it + 1) * 32, b ^ 1);
        }
        bf16x8 af[4], bfr[2];
        #pragma unroll
        for (int i = 0; i < 4; ++i)
            af[i] = *(const bf16x8*)(As[b] + (i * 16 + l16) * 32 + quad * 8);
        #pragma unroll
        for (int j = 0; j < 2; ++j)
            bfr[j] = *(const bf16x8*)(Bs[b] + (wave * 32 + j * 16 + l16) * 32 + quad * 8);
        #pragma unroll
        for (int i = 0; i < 4; ++i)
            #pragma unroll
            for (int j = 0; j < 2; ++j)
                acc[i][j] = __builtin_amdgcn_mfma_f32_16x16x32_bf16(af[i], bfr[j], acc[i][j], 0, 0, 0);
    }

    #pragma unroll
    for (int i = 0; i < 4; ++i) {
        int rbase = m0 + i * 16 + quad * 4;
        #pragma unroll
        for (int j = 0; j < 2; ++j) {
            int col = n0 + wave * 32 + j * 16 + l16;
            #pragma unroll
            for (int r = 0; r < 4; ++r) {
                size_t o = (size_t)(rbase + r) * HID + col;
                Cf[o] = acc[i][j][r] + Xres[o];
            }
        }
    }
}

// ---------------- flash attention: 128 queries x one (head, key-split) ----------------
// R8 inner loop EXACTLY (proven 85us). head-0: Kc/Vtc compacted (3 splits); head-1:
// Kb1/Vt1 (5 splits, CH1=832). Validity = (key < nact); tails P-gated to 0.
__global__ __launch_bounds__(512, 2)
void k_flash(const unsigned short* __restrict__ Q,
             const unsigned short* __restrict__ Kb1,
             const unsigned short* __restrict__ Vt1,
             const unsigned short* __restrict__ Kc,
             const unsigned short* __restrict__ Vtc,
             const int* __restrict__ nactp,
             unsigned short* __restrict__ Opart,       // [8][S][512] per-head local cols
             float* __restrict__ Lbuf) {               // [8][S]
    __shared__ unsigned short Ks[2][32 * KS_STRIDE];
    __shared__ __bf16 Ps[2][128][40];
    int tid  = threadIdx.x;
    int wave = tid >> 6, lane = tid & 63;
    int quad = lane >> 4, l16 = lane & 15;
    int x = blockIdx.x, qtile = blockIdx.y;
    int head  = (x >= 3) ? 1 : 0;
    int split = head ? x - 3 : x;
    int nact  = nactp[0];

    int nit, base, vrs;
    const unsigned short *Ksrc, *Vsrc;
    if (head == 0) {
        nit  = (nact + 95) / 96;          // ceil(nact / (3 splits * 32))
        base = split * nit * 32;
        Ksrc = Kc;  Vsrc = Vtc; vrs = PADK;
    } else {
        base = split * CH1;
        nit  = min(CH1 >> 5, (S_LEN - base) >> 5);
        Ksrc = Kb1; Vsrc = Vt1; vrs = S_LEN;
    }

    // Q fragments (A-operand: A[m=lane&15][k=quad*8+j]), pinned in registers
    int qrow = qtile * 128 + wave * 16 + l16;
    const unsigned short* qp = Q + qrow * HID + head * HDIM;
    bf16x8 qf[16];
    #pragma unroll
    for (int t = 0; t < 16; ++t) qf[t] = *(const bf16x8*)(qp + t * 32 + quad * 8);

    float lsum[4];
    #pragma unroll
    for (int r = 0; r < 4; ++r) lsum[r] = 0.f;
    f32x4 zero = {0.f, 0.f, 0.f, 0.f};
    f32x4 oacc[8][4];
    #pragma unroll
    for (int mt = 0; mt < 8; ++mt)
        #pragma unroll
        for (int nt = 0; nt < 4; ++nt) oacc[mt][nt] = zero;

    const float scale = 0.044194173824159216f; // 1/sqrt(512)
    const unsigned short* vptr = Vsrc + (size_t)(wave * 64 + l16) * vrs + base + quad * 8;

    auto stageK = [&](int kt, int buf) {
        int kb = base + kt * 32;
        #pragma unroll
        for (int i = 0; i < 4; ++i) {
            int c = tid + i * 512;
            int row = c >> 6, col = (c & 63) * 8;   // per-wave: row uniform, col = lane*16B
            async_cp16(Ksrc + (size_t)(kb + row) * 512 + col, &Ks[buf][row * KS_STRIDE + col]);
        }
    };

    if (nit > 0) stageK(0, 0);

    bf16x8 vf[4];
    for (int it = 0; it < nit; ++it) {
        int cur = it & 1;
        __syncthreads();   // Ks[cur] DMA drained; Ps[cur] free; Ps[cur^1] written

        if (it + 1 < nit) stageK(it + 1, cur ^ 1);

        __builtin_amdgcn_s_setprio(1);
        if (it > 0) {
            #pragma unroll
            for (int mt = 0; mt < 8; ++mt) {
                bf16x8 pf = *(const bf16x8*)&Ps[cur ^ 1][mt * 16 + l16][quad * 8];
                #pragma unroll
                for (int nt = 0; nt < 4; ++nt)
                    oacc[mt][nt] = __builtin_amdgcn_mfma_f32_16x16x32_bf16(pf, vf[nt], oacc[mt][nt], 0, 0, 0);
            }
        }

        // V prefetch for THIS tile (16 VGPR carry, proven budget)
        #pragma unroll
        for (int nt = 0; nt < 4; ++nt)
            vf[nt] = *(const bf16x8*)(vptr + (size_t)nt * 16 * vrs + it * 32);

        // S = Q K^T
        f32x4 sacc[2];
        sacc[0] = zero; sacc[1] = zero;
        #pragma unroll
        for (int nt = 0; nt < 2; ++nt)
            #pragma unroll
            for (int t = 0; t < 16; ++t) {
                bf16x8 kf = *(const bf16x8*)&Ks[cur][(nt * 16 + l16) * KS_STRIDE + t * 32 + quad * 8];
                sacc[nt] = __builtin_amdgcn_mfma_f32_16x16x32_bf16(qf[t], kf, sacc[nt], 0, 0, 0);
            }
        __builtin_amdgcn_s_setprio(0);

        // validity: compacted head-0 keys need only the nact bound; head-1 all valid
        bool keep0 = true, keep1 = true;
        if (head == 0) {
            int kb = base + it * 32;
            keep0 = kb + l16 < nact;
            keep1 = kb + 16 + l16 < nact;
        }
        #pragma unroll
        for (int r = 0; r < 4; ++r) {
            float p0 = keep0 ? __expf(fminf(sacc[0][r] * scale, 30.f)) : 0.f;
            float p1 = keep1 ? __expf(fminf(sacc[1][r] * scale, 30.f)) : 0.f;
            lsum[r] += p0 + p1;
            Ps[cur][wave * 16 + quad * 4 + r][l16]      = (__bf16)p0;
            Ps[cur][wave * 16 + quad * 4 + r][16 + l16] = (__bf16)p1;
        }
    }

    // epilogue PV for the last tile
    if (nit > 0) {
        int lastb = (nit - 1) & 1;
        __syncthreads();
        #pragma unroll
        for (int mt = 0; mt < 8; ++mt) {
            bf16x8 pf = *(const bf16x8*)&Ps[lastb][mt * 16 + l16][quad * 8];
            #pragma unroll
            for (int nt = 0; nt < 4; ++nt)
                oacc[mt][nt] = __builtin_amdgcn_mfma_f32_16x16x32_bf16(pf, vf[nt], oacc[mt][nt], 0, 0, 0);
        }
    }

    // l-reduction across the 16 lanes of this quad
    #pragma unroll
    for (int r = 0; r < 4; ++r) {
        float s = lsum[r];
        #pragma unroll
        for (int off = 1; off < 16; off <<= 1)
            s += __shfl_xor(s, off, 64);
        lsum[r] = s;
    }
    int slot = head ? 3 + split : split;
    int lrow = qtile * 128 + wave * 16 + quad * 4;
    if (l16 == 0) {
        #pragma unroll
        for (int r = 0; r < 4; ++r)
            Lbuf[slot * S_LEN + lrow + r] = lsum[r];
    }
    // O epilogue: per-head local cols (512-wide)
    unsigned short* op = Opart + (size_t)slot * S_LEN * 512;
    #pragma unroll
    for (int mt = 0; mt < 8; ++mt)
        #pragma unroll
        for (int nt = 0; nt < 4; ++nt)
            #pragma unroll
            for (int r = 0; r < 4; ++r)
                op[(qtile * 128 + mt * 16 + quad * 4 + r) * 512 +
                   wave * 64 + nt * 16 + l16] = f2b(oacc[mt][nt][r]);
}

// ---------------- per-row LayerNorm over H=1024 (fp32 in, fp32 out) ----------------
__global__ __launch_bounds__(256)
void k_ln(const float* __restrict__ res,
          const float* __restrict__ w,
          const float* __restrict__ b,
          float* __restrict__ out) {
    __shared__ float red[8];
    int s = blockIdx.x, tid = threadIdx.x;
    const float* row = res + s * HID;
    float x[4], s1 = 0.f, s2 = 0.f;
    #pragma unroll
    for (int i = 0; i < 4; ++i) {
        x[i] = row[tid + i * 256];
        s1 += x[i]; s2 += x[i] * x[i];
    }
    #pragma unroll
    for (int off = 1; off < 64; off <<= 1) {
        s1 += __shfl_xor(s1, off, 64);
        s2 += __shfl_xor(s2, off, 64);
    }
    int wave = tid >> 6;
    if ((tid & 63) == 0) { red[wave] = s1; red[4 + wave] = s2; }
    __syncthreads();
    s1 = red[0] + red[1] + red[2] + red[3];
    s2 = red[4] + red[5] + red[6] + red[7];
    float mu   = s1 * (1.f / HID);
    float var  = s2 * (1.f / HID) - mu * mu;
    float rstd = rsqrtf(var + LN_EPS);
    #pragma unroll
    for (int i = 0; i < 4; ++i) {
        int col = tid + i * 256;
        out[s * HID + col] = (x[i] - mu) * rstd * w[col] + b[col];
    }
}

extern "C" void kernel_launch(void* const* d_in, const int* in_sizes, int n_in,
                              void* d_out, int out_size, void* d_ws, size_t ws_size,
                              hipStream_t stream) {
    const float* X   = (const float*)d_in[0];
    const float* sd  = (const float*)d_in[1];
    const int*   msk = (const int*)d_in[2];
    const float* Wq  = (const float*)d_in[3];
    const float* Wk  = (const float*)d_in[4];
    const float* Wv  = (const float*)d_in[5];
    const float* Wo  = (const float*)d_in[6];
    const float* Wsp = (const float*)d_in[7];
    const float* bsp = (const float*)d_in[8];
    const float* lw  = (const float*)d_in[9];
    const float* lb  = (const float*)d_in[10];
    float* out = (float*)d_out;

    // Workspace map — 89MB proven envelope (R7 lesson).
    char* ws = (char*)d_ws;
    const size_t MB = 1ull << 20;
    float*          semb  = (float*)(ws);                     // 4 KB @0
    int*            cidx  = (int*)(ws + (16 << 10));          // 16.9 KB @16K (PADK ints)
    int*            nactp = (int*)(ws + (48 << 10));          // 4 B @48K
    float*          Lbuf  = (float*)(ws + (1ull << 16));      // 128 KB @64K (8 slots x S)
    float*          kbias = (float*)(ws + (208 << 10));       // 4 KB @208K
    float*          vbias = (float*)(ws + (212 << 10));       // 4 KB @212K
    unsigned short* Xb    = (unsigned short*)(ws + 1 * MB);   // 8 MB
    unsigned short* Qb    = (unsigned short*)(ws + 17 * MB);  // 8 MB
    unsigned short* Kb1   = (unsigned short*)(ws + 25 * MB);  // 4 MB [S][512]
    unsigned short* Vt1   = (unsigned short*)(ws + 29 * MB);  // 4 MB [512][S]
    unsigned short* Kc    = (unsigned short*)(ws + 33 * MB);  // 4.125 MB [PADK][512]
    unsigned short* Vtc   = (unsigned short*)(ws + 37 * MB + (256 << 10)); // 4.125 MB
    unsigned short* Wqb   = (unsigned short*)(ws + 49 * MB);  // 2 MB
    unsigned short* Wkb   = (unsigned short*)(ws + 51 * MB);  // 2 MB
    unsigned short* Wvb   = (unsigned short*)(ws + 53 * MB);  // 2 MB
    unsigned short* Wob   = (unsigned short*)(ws + 55 * MB);  // 2 MB
    float*          resf  = (float*)(ws + 17 * MB);           // 16 MB over dead Qb/Kb1/Vt1
    unsigned short* Opart = (unsigned short*)(ws + 57 * MB);  // 32 MB [8][S][512] -> 89 MB

    // fused front-end: weights cvt + semb + scan + Xb cvt + kbias/vbias (4109 blocks)
    k_cvt4s<<<dim3(4109), dim3(256), 0, stream>>>(
        Wq, Wk, Wv, Wo, Wqb, Wkb, Wvb, Wob, Wsp, sd, bsp, semb, msk, cidx, nactp,
        X, Xb, Wk, Wv, kbias, vbias);

    // all projections (Q, K/V head-1, compacted K/V head-0; bias tables; early-exit)
    k_gemms<<<dim3(776), dim3(256), 0, stream>>>(
        Xb, Wqb, Wkb, Wvb, cidx, nactp, kbias, vbias, Qb, Kb1, Vt1, Kc, Vtc);

    // asymmetric splits: x 0..2 = head0 (compacted), x 3..7 = head1; y = qtile (32)
    k_flash<<<dim3(8, S_LEN / 128), dim3(512), 0, stream>>>(
        Qb, Kb1, Vt1, Kc, Vtc, nactp, Opart, Lbuf);

    // out-projection with fused split-combine + normalize + residual
    k_gemm_o<<<dim3(512), dim3(256), 0, stream>>>(Opart, Lbuf, Wob, resf, X);
    k_ln<<<dim3(S_LEN), dim3(256), 0, stream>>>(resf, lw, lb, out);
}